// Round 15
// baseline (78.655 us; speedup 1.0000x reference)
//
#include <hip/hip_runtime.h>
#include <hip/hip_bf16.h>
#include <hip/hip_cooperative_groups.h>

namespace cg = cooperative_groups;

#define NB 32
#define TS 300
#define NBATCH 16384
#define DTF (1.0f/300.0f)
#define A_ELEMS (NBATCH*2*TS)   /* 9,830,400 */

typedef __attribute__((ext_vector_type(8))) short bf16x8;
typedef __attribute__((ext_vector_type(4))) float f32x4;

static __device__ __forceinline__ ushort f2bf(float f) {
    union { __hip_bfloat16 h; ushort u; } cv;
    cv.h = __float2bfloat16(f);
    return cv.u;
}

// ws layout (bytes):
//   0      : wsPhi  19*64 uint4 = 19456 B   (phi A-fragments, bf16)
//   32768  : pbuf   32768 float4 = 512 KB   ({goal, az, y0, v} per channel)
//   557056 : wbuf16 32768*32 bf16 = 2 MB    (prescaled basis weights = DTF*kfac*w)

// Cooperative kernel: R12's two proven kernels concatenated with grid.sync().
// Phase A: blocks 0..255 = R12 k_head body (verbatim, global handoff);
//          block 256 = phi table; blocks 257..511 idle to the sync.
// Phase B: all 512 blocks = R12 k_roll body (verbatim).
__global__ __launch_bounds__(256) void k_all(
    const float* __restrict__ state,
    const float* __restrict__ fc1_w, const float* __restrict__ fc1_b,
    const float* __restrict__ fc2m_w, const float* __restrict__ fc2m_b,
    const float* __restrict__ sig_w, const float* __restrict__ sig_b,
    const float* __restrict__ val_w, const float* __restrict__ val_b,
    const float* __restrict__ dmp_c, const float* __restrict__ dmp_s2,
    float* __restrict__ sig_out, float* __restrict__ pbuf,
    ushort* __restrict__ wbuf16, uint4* __restrict__ wsPhi,
    float* __restrict__ a_out, float* __restrict__ v_out)
{
    __shared__ uint4 bfr[640];          // 10,240 B
    __shared__ float f1s[64*4];         //  1,024 B
    __shared__ float biasl[80];         //    320 B
    __shared__ float hlds[4*16*68];     // 17,408 B
    __shared__ float ct[4*16*84];       // 21,504 B
    __shared__ float scl[4][16][2];     //    512 B   (total 51,008 B)

    const int tid = threadIdx.x;
    const int bid = blockIdx.x;

    if (bid == 256) {
        // ---- phase A (block 256): phi A-fragment table -> ws ----
        const float l2 = log2f(1.0f - DTF);
        for (int t = tid; t < 304; t += 256) {
            ushort row[NB];
            if (t < TS) {
                const float x = exp2f((float)(t + 1) * l2);
                float ps[NB]; float s = 0.0f;
                #pragma unroll
                for (int n = 0; n < NB; ++n) {
                    float d = x - dmp_c[n];
                    float p = __expf(-0.5f * d * d / dmp_s2[n]);
                    ps[n] = p; s += p;
                }
                const float inv = x / s;
                #pragma unroll
                for (int n = 0; n < NB; ++n) row[n] = f2bf(ps[n] * inv);
            } else {
                #pragma unroll
                for (int n = 0; n < NB; ++n) row[n] = 0;
            }
            #pragma unroll
            for (int g0 = 0; g0 < 4; ++g0) {
                union { ushort us[8]; uint4 v; } pk;
                #pragma unroll
                for (int e = 0; e < 8; ++e) pk.us[e] = row[g0*8 + e];
                wsPhi[(t >> 4)*64 + g0*16 + (t & 15)] = pk.v;
            }
        }
    } else if (bid < 256) {
        // ---- phase A (blocks 0..255): MFMA heads (R12 verbatim) ----
        const int wv  = tid >> 6;
        const int l   = tid & 63;
        const int b16 = l & 15;
        const int g   = l >> 4;

        for (int e = tid; e < 640; e += 256) {
            const int T = e >> 7, kk = (e >> 6) & 1, lane = e & 63;
            const int r = T*16 + (lane & 15);
            const int k0 = kk*32 + (lane >> 4)*8;
            union { ushort us[8]; uint4 v; } pk;
            if (r < 70) {
                const float* src = (r < 66) ? (fc2m_w + r*64 + k0)
                                 : (r < 68) ? (sig_w + (r-66)*64 + k0)
                                 : (val_w + (r-68)*64 + k0);
                #pragma unroll
                for (int i = 0; i < 8; ++i) pk.us[i] = f2bf(src[i]);
            } else {
                #pragma unroll
                for (int i = 0; i < 8; ++i) pk.us[i] = 0;
            }
            bfr[e] = pk.v;
        }
        if (tid < 64) {
            f1s[tid*4+0] = fc1_w[tid*3+0];
            f1s[tid*4+1] = fc1_w[tid*3+1];
            f1s[tid*4+2] = fc1_w[tid*3+2];
            f1s[tid*4+3] = fc1_b[tid];
        }
        if (tid < 80) biasl[tid] = (tid < 66) ? fc2m_b[tid] : (tid < 68) ? sig_b[tid-66]
                                 : (tid < 70) ? val_b[tid-68] : 0.0f;
        __syncthreads();

        const int bbase = bid*64 + wv*16;
        const int bglob = bbase + b16;
        const float s0 = state[bglob*3+0], s1 = state[bglob*3+1], s2 = state[bglob*3+2];

        float* hrow = hlds + wv*1088 + b16*68;
        #pragma unroll
        for (int i = 0; i < 16; ++i) {
            const int hid = g + 4*i;
            const float4 fw = *(const float4*)(f1s + hid*4);
            const float pre = fmaf(fw.x, s0, fmaf(fw.y, s1, fmaf(fw.z, s2, fw.w)));
            const float e = __expf(2.0f * pre);
            hrow[hid] = (1.0f - 2.0f/(e + 1.0f)) * 0.1f;   // tanh, overflow-safe
        }

        bf16x8 A0, A1;
        {
            const float* hr = hlds + wv*1088 + b16*68 + g*8;
            const float4 h0 = *(const float4*)(hr),      h1 = *(const float4*)(hr + 4);
            const float4 h2 = *(const float4*)(hr + 32), h3 = *(const float4*)(hr + 36);
            union { bf16x8 v; ushort u[8]; } p0, p1;
            p0.u[0]=f2bf(h0.x); p0.u[1]=f2bf(h0.y); p0.u[2]=f2bf(h0.z); p0.u[3]=f2bf(h0.w);
            p0.u[4]=f2bf(h1.x); p0.u[5]=f2bf(h1.y); p0.u[6]=f2bf(h1.z); p0.u[7]=f2bf(h1.w);
            p1.u[0]=f2bf(h2.x); p1.u[1]=f2bf(h2.y); p1.u[2]=f2bf(h2.z); p1.u[3]=f2bf(h2.w);
            p1.u[4]=f2bf(h3.x); p1.u[5]=f2bf(h3.y); p1.u[6]=f2bf(h3.z); p1.u[7]=f2bf(h3.w);
            A0 = p0.v; A1 = p1.v;
        }

        float* ctw = ct + wv*1344;
        const f32x4 zacc = {0.0f, 0.0f, 0.0f, 0.0f};
        #pragma unroll
        for (int T = 0; T < 5; ++T) {
            union { uint4 q; bf16x8 v; } B0, B1;
            B0.q = bfr[(T*2+0)*64 + l];
            B1.q = bfr[(T*2+1)*64 + l];
            f32x4 acc = __builtin_amdgcn_mfma_f32_16x16x32_bf16(A0, B0.v, zacc, 0, 0, 0);
            acc = __builtin_amdgcn_mfma_f32_16x16x32_bf16(A1, B1.v, acc, 0, 0, 0);
            const int r = T*16 + b16;
            const float bs = biasl[r];
            #pragma unroll
            for (int reg = 0; reg < 4; ++reg)
                ctw[(g*4 + reg)*84 + r] = acc[reg] + bs;
        }

        if (l < 32) {
            const int b = l & 15, d = l >> 4;
            const float goal = ctw[b*84 + d];
            const float y0 = state[(bbase + b)*3 + d];
            scl[wv][b][d] = DTF * (goal - y0);
        }

        uint* wout = (uint*)wbuf16;
        #pragma unroll 1
        for (int b = 0; b < 16; ++b) {
            if (l < 32) {
                const float2 wp = *(const float2*)(ctw + b*84 + 2 + 2*l);
                const float sc = scl[wv][b][l >> 4];
                wout[(bbase + b)*32 + l] =
                    (uint)f2bf(wp.x * sc) | ((uint)f2bf(wp.y * sc) << 16);
            }
        }
        if (l < 16) {
            const float* cb = ctw + l*84;
            const float az = fminf(fmaxf(cb[65], 0.5f), 30.0f);
            const float y0 = state[(bbase + l)*3 + 0];
            *(float4*)(pbuf + ((bbase + l)*2 + 0)*4) = make_float4(cb[0], az, y0, cb[68]);
        } else if (l < 32) {
            const int b = l - 16;
            const float* cb = ctw + b*84;
            const float az = fminf(fmaxf(cb[65], 0.5f), 30.0f);
            const float y0 = state[(bbase + b)*3 + 1];
            *(float4*)(pbuf + ((bbase + b)*2 + 1)*4) = make_float4(cb[1], az, y0, cb[69]);
        } else if (l < 48) {
            const int b = l - 32;
            const float* cb = ctw + b*84;
            const float sg0 = 1.0f / (1.0f + __expf(-cb[66])) + 0.001f;
            const float sg1 = 1.0f / (1.0f + __expf(-cb[67])) + 0.001f;
            *(float2*)(sig_out + (bbase + b)*2) = make_float2(sg0, sg1);
        }
    }
    // blocks 257..511: no phase-A work

    cg::this_grid().sync();

    // ---- phase B (all 512 blocks): rollout (R12 k_roll verbatim) ----
    {
        const int wv = tid >> 6;
        const int j  = tid & 63;
        const int ch = j & 15;
        const int g  = j >> 4;
        const int m  = (bid << 6) + (wv << 4) + ch;

        const float4 pp = *(const float4*)(pbuf + m*4);   // {goal, az, y0, v}
        const float az = pp.y;
        const float Ac = (DTF * 0.25f) * az * az;
        const float OmB = fmaf(-DTF, az, 1.0f);
        const float c0 = Ac * pp.x;
        float y = pp.z;                                   // y0
        float z = 0.01f;
        const f32x4 cvec = {c0, c0, c0, c0};

        const bf16x8 wb = *(const bf16x8*)(wbuf16 + m*NB + g*8);   // prescaled
        const bf16x8* ap = (const bf16x8*)wsPhi;
        bf16x8 af = ap[j];

        float* aptr = a_out + m*TS + (g << 2);
        float* vptr = v_out + m*TS + (g << 2);
        const float4 vsp = make_float4(pp.w, pp.w, pp.w, pp.w);

        for (int c = 0; c < 19; ++c) {
            const bool st = (c < 18) | (g < 3);
            if (st) { *(float4*)vptr = vsp; }             // drains under compute
            vptr += 16;

            f32x4 facc = __builtin_amdgcn_mfma_f32_16x16x32_bf16(af, wb, cvec, 0, 0, 0);
            if (c < 18) af = ap[(c + 1)*64 + j];

            // all-gather F'[0..15] across the 4 g-groups (channel-preserving)
            float F[16];
            #pragma unroll
            for (int q = 0; q < 4; ++q) {
                float a = facc[q], b = facc[q];
                asm volatile("v_permlane16_swap_b32 %0, %1" : "+v"(a), "+v"(b));
                float a2 = a, b2 = b;
                asm volatile("v_permlane32_swap_b32 %0, %1" : "+v"(a), "+v"(a2));
                asm volatile("v_permlane32_swap_b32 %0, %1" : "+v"(b), "+v"(b2));
                F[0*4+q] = a; F[1*4+q] = b; F[2*4+q] = a2; F[3*4+q] = b2;
            }

            float avq[4];
            #pragma unroll
            for (int i = 0; i < 16; ++i) {
                const float t2 = fmaf(-Ac, y, F[i]);       // F already = c0 + Kc*F
                if (g == (i >> 2)) avq[i & 3] = z;         // raw z; DTF at store
                y = fmaf(DTF, z, y);
                z = fmaf(OmB, z, t2);
            }

            if (st) {
                *(float4*)aptr = make_float4(avq[0]*DTF, avq[1]*DTF, avq[2]*DTF, avq[3]*DTF);
            }
            aptr += 16;
        }
    }
}

extern "C" void kernel_launch(void* const* d_in, const int* in_sizes, int n_in,
                              void* d_out, int out_size, void* d_ws, size_t ws_size,
                              hipStream_t stream) {
    (void)in_sizes; (void)n_in; (void)out_size; (void)ws_size;
    const float* state  = (const float*)d_in[0];
    const float* fc1_w  = (const float*)d_in[1];
    const float* fc1_b  = (const float*)d_in[2];
    const float* fc2m_w = (const float*)d_in[3];
    const float* fc2m_b = (const float*)d_in[4];
    const float* sig_w  = (const float*)d_in[5];
    const float* sig_b  = (const float*)d_in[6];
    const float* val_w  = (const float*)d_in[7];
    const float* val_b  = (const float*)d_in[8];
    const float* dmp_c  = (const float*)d_in[9];
    const float* dmp_s2 = (const float*)d_in[10];

    float* out     = (float*)d_out;
    float* a_out   = out;
    float* sig_out = out + A_ELEMS;
    float* v_out   = out + A_ELEMS + NBATCH*2;

    char* ws = (char*)d_ws;
    uint4*  wsPhi  = (uint4*)ws;
    float*  pbuf   = (float*)(ws + 32768);
    ushort* wbuf16 = (ushort*)(ws + 557056);

    void* args[] = {
        (void*)&state, (void*)&fc1_w, (void*)&fc1_b, (void*)&fc2m_w, (void*)&fc2m_b,
        (void*)&sig_w, (void*)&sig_b, (void*)&val_w, (void*)&val_b,
        (void*)&dmp_c, (void*)&dmp_s2,
        (void*)&sig_out, (void*)&pbuf, (void*)&wbuf16, (void*)&wsPhi,
        (void*)&a_out, (void*)&v_out
    };
    hipLaunchCooperativeKernel((void*)k_all, dim3(512), dim3(256), args, 0, stream);
}

// Round 16
// 27.960 us; speedup vs baseline: 2.8131x; 2.8131x over previous
//
#include <hip/hip_runtime.h>
#include <hip/hip_bf16.h>

#define NB 32
#define TS 300
#define NBATCH 16384
#define DTF (1.0f/300.0f)
#define A_ELEMS (NBATCH*2*TS)   /* 9,830,400 */

typedef __attribute__((ext_vector_type(8))) short bf16x8;
typedef __attribute__((ext_vector_type(4))) float f32x4;

static __device__ __forceinline__ ushort f2bf(float f) {
    union { __hip_bfloat16 h; ushort u; } cv;
    cv.h = __float2bfloat16(f);
    return cv.u;
}

// ws layout (bytes):
//   0      : wsPhi  19*64 uint4 = 19456 B   (phi A-fragments, bf16)
//   32768  : pbuf   32768 float4 = 512 KB   ({goal, az, y0, v} per channel)
//   557056 : wbuf16 32768*32 bf16 = 2 MB    (prescaled basis weights = DTF*kfac*w)

// ---------------- kernel 1: MFMA heads (blocks 0..255) + phi (block 256) ----------------
// (R12 verbatim — proven)
__global__ __launch_bounds__(256) void k_head(
    const float* __restrict__ state,
    const float* __restrict__ fc1_w, const float* __restrict__ fc1_b,
    const float* __restrict__ fc2m_w, const float* __restrict__ fc2m_b,
    const float* __restrict__ sig_w, const float* __restrict__ sig_b,
    const float* __restrict__ val_w, const float* __restrict__ val_b,
    const float* __restrict__ dmp_c, const float* __restrict__ dmp_s2,
    float* __restrict__ sig_out, float* __restrict__ pbuf,
    ushort* __restrict__ wbuf16, uint4* __restrict__ wsPhi)
{
    const int tid = threadIdx.x;
    if (blockIdx.x == 256) {
        const float l2 = log2f(1.0f - DTF);
        for (int t = tid; t < 304; t += 256) {
            ushort row[NB];
            if (t < TS) {
                const float x = exp2f((float)(t + 1) * l2);
                float ps[NB]; float s = 0.0f;
                #pragma unroll
                for (int n = 0; n < NB; ++n) {
                    float d = x - dmp_c[n];
                    float p = __expf(-0.5f * d * d / dmp_s2[n]);
                    ps[n] = p; s += p;
                }
                const float inv = x / s;
                #pragma unroll
                for (int n = 0; n < NB; ++n) row[n] = f2bf(ps[n] * inv);
            } else {
                #pragma unroll
                for (int n = 0; n < NB; ++n) row[n] = 0;
            }
            #pragma unroll
            for (int g0 = 0; g0 < 4; ++g0) {
                union { ushort us[8]; uint4 v; } pk;
                #pragma unroll
                for (int e = 0; e < 8; ++e) pk.us[e] = row[g0*8 + e];
                wsPhi[(t >> 4)*64 + g0*16 + (t & 15)] = pk.v;
            }
        }
        return;
    }

    __shared__ uint4 bfr[640];
    __shared__ float f1s[64*4];
    __shared__ float biasl[80];
    __shared__ float hlds[4*16*68];
    __shared__ float ct[4*16*84];
    __shared__ float scl[4][16][2];

    const int wv  = tid >> 6;
    const int l   = tid & 63;
    const int b16 = l & 15;
    const int g   = l >> 4;

    for (int e = tid; e < 640; e += 256) {
        const int T = e >> 7, kk = (e >> 6) & 1, lane = e & 63;
        const int r = T*16 + (lane & 15);
        const int k0 = kk*32 + (lane >> 4)*8;
        union { ushort us[8]; uint4 v; } pk;
        if (r < 70) {
            const float* src = (r < 66) ? (fc2m_w + r*64 + k0)
                             : (r < 68) ? (sig_w + (r-66)*64 + k0)
                             : (val_w + (r-68)*64 + k0);
            #pragma unroll
            for (int i = 0; i < 8; ++i) pk.us[i] = f2bf(src[i]);
        } else {
            #pragma unroll
            for (int i = 0; i < 8; ++i) pk.us[i] = 0;
        }
        bfr[e] = pk.v;
    }
    if (tid < 64) {
        f1s[tid*4+0] = fc1_w[tid*3+0];
        f1s[tid*4+1] = fc1_w[tid*3+1];
        f1s[tid*4+2] = fc1_w[tid*3+2];
        f1s[tid*4+3] = fc1_b[tid];
    }
    if (tid < 80) biasl[tid] = (tid < 66) ? fc2m_b[tid] : (tid < 68) ? sig_b[tid-66]
                             : (tid < 70) ? val_b[tid-68] : 0.0f;
    __syncthreads();

    const int bbase = blockIdx.x*64 + wv*16;
    const int bglob = bbase + b16;
    const float s0 = state[bglob*3+0], s1 = state[bglob*3+1], s2 = state[bglob*3+2];

    float* hrow = hlds + wv*1088 + b16*68;
    #pragma unroll
    for (int i = 0; i < 16; ++i) {
        const int hid = g + 4*i;
        const float4 fw = *(const float4*)(f1s + hid*4);
        const float pre = fmaf(fw.x, s0, fmaf(fw.y, s1, fmaf(fw.z, s2, fw.w)));
        const float e = __expf(2.0f * pre);
        hrow[hid] = (1.0f - 2.0f/(e + 1.0f)) * 0.1f;   // tanh, overflow-safe
    }

    bf16x8 A0, A1;
    {
        const float* hr = hlds + wv*1088 + b16*68 + g*8;
        const float4 h0 = *(const float4*)(hr),      h1 = *(const float4*)(hr + 4);
        const float4 h2 = *(const float4*)(hr + 32), h3 = *(const float4*)(hr + 36);
        union { bf16x8 v; ushort u[8]; } p0, p1;
        p0.u[0]=f2bf(h0.x); p0.u[1]=f2bf(h0.y); p0.u[2]=f2bf(h0.z); p0.u[3]=f2bf(h0.w);
        p0.u[4]=f2bf(h1.x); p0.u[5]=f2bf(h1.y); p0.u[6]=f2bf(h1.z); p0.u[7]=f2bf(h1.w);
        p1.u[0]=f2bf(h2.x); p1.u[1]=f2bf(h2.y); p1.u[2]=f2bf(h2.z); p1.u[3]=f2bf(h2.w);
        p1.u[4]=f2bf(h3.x); p1.u[5]=f2bf(h3.y); p1.u[6]=f2bf(h3.z); p1.u[7]=f2bf(h3.w);
        A0 = p0.v; A1 = p1.v;
    }

    float* ctw = ct + wv*1344;
    const f32x4 zacc = {0.0f, 0.0f, 0.0f, 0.0f};
    #pragma unroll
    for (int T = 0; T < 5; ++T) {
        union { uint4 q; bf16x8 v; } B0, B1;
        B0.q = bfr[(T*2+0)*64 + l];
        B1.q = bfr[(T*2+1)*64 + l];
        f32x4 acc = __builtin_amdgcn_mfma_f32_16x16x32_bf16(A0, B0.v, zacc, 0, 0, 0);
        acc = __builtin_amdgcn_mfma_f32_16x16x32_bf16(A1, B1.v, acc, 0, 0, 0);
        const int r = T*16 + b16;
        const float bs = biasl[r];
        #pragma unroll
        for (int reg = 0; reg < 4; ++reg)
            ctw[(g*4 + reg)*84 + r] = acc[reg] + bs;
    }

    if (l < 32) {
        const int b = l & 15, d = l >> 4;
        const float goal = ctw[b*84 + d];
        const float y0 = state[(bbase + b)*3 + d];
        scl[wv][b][d] = DTF * (goal - y0);
    }

    uint* wout = (uint*)wbuf16;
    #pragma unroll 1
    for (int b = 0; b < 16; ++b) {
        if (l < 32) {
            const float2 wp = *(const float2*)(ctw + b*84 + 2 + 2*l);
            const float sc = scl[wv][b][l >> 4];
            wout[(bbase + b)*32 + l] =
                (uint)f2bf(wp.x * sc) | ((uint)f2bf(wp.y * sc) << 16);
        }
    }
    if (l < 16) {
        const float* cb = ctw + l*84;
        const float az = fminf(fmaxf(cb[65], 0.5f), 30.0f);
        const float y0 = state[(bbase + l)*3 + 0];
        *(float4*)(pbuf + ((bbase + l)*2 + 0)*4) = make_float4(cb[0], az, y0, cb[68]);
    } else if (l < 32) {
        const int b = l - 16;
        const float* cb = ctw + b*84;
        const float az = fminf(fmaxf(cb[65], 0.5f), 30.0f);
        const float y0 = state[(bbase + b)*3 + 1];
        *(float4*)(pbuf + ((bbase + b)*2 + 1)*4) = make_float4(cb[1], az, y0, cb[69]);
    } else if (l < 48) {
        const int b = l - 32;
        const float* cb = ctw + b*84;
        const float sg0 = 1.0f / (1.0f + __expf(-cb[66])) + 0.001f;
        const float sg1 = 1.0f / (1.0f + __expf(-cb[67])) + 0.001f;
        *(float2*)(sig_out + (bbase + b)*2) = make_float2(sg0, sg1);
    }
}

// ---------------- kernel 2: rollout + dedicated v-streamer waves ----------------
// Waves 0-3: R12 rollout body, a-stores only (compute waves never issue the
// 39 MB of v traffic). Waves 4-5: stream v rows for the block's 64 channels
// (no compute dependency; saturates write BW concurrently). 384 thr/block,
// 12 waves/CU at 2 blocks/CU.
__global__ __launch_bounds__(384) void k_roll(
    const uint4* __restrict__ wsPhi, const float* __restrict__ pbuf,
    const ushort* __restrict__ wbuf16, float* __restrict__ a_out,
    float* __restrict__ v_out)
{
    const int tid = threadIdx.x;
    const int wv = tid >> 6;
    const int l  = tid & 63;

    if (wv >= 4) {
        // ---- v-streamer: 2 waves x 32 channels ----
        const int vw = wv - 4;
        const int mbase = (blockIdx.x << 6) + (vw << 5);
        #pragma unroll 1
        for (int r = 0; r < 32; ++r) {
            const int mch = mbase + r;
            const float fv = pbuf[mch*4 + 3];
            float4* vrow = (float4*)(v_out + mch*TS);
            const float4 vq = make_float4(fv, fv, fv, fv);
            vrow[l] = vq;
            if (l < 11) vrow[64 + l] = vq;
        }
        return;
    }

    const int ch = l & 15;
    const int g  = l >> 4;
    const int m  = (blockIdx.x << 6) + (wv << 4) + ch;

    const float4 pp = *(const float4*)(pbuf + m*4);   // {goal, az, y0, v}
    const float az = pp.y;
    const float Ac = (DTF * 0.25f) * az * az;
    const float OmB = fmaf(-DTF, az, 1.0f);
    const float c0 = Ac * pp.x;
    float y = pp.z;                                   // y0
    float z = 0.01f;
    const f32x4 cvec = {c0, c0, c0, c0};

    const bf16x8 wb = *(const bf16x8*)(wbuf16 + m*NB + g*8);   // prescaled
    const bf16x8* ap = (const bf16x8*)wsPhi;
    bf16x8 af = ap[l];

    float* aptr = a_out + m*TS + (g << 2);

    for (int c = 0; c < 19; ++c) {
        f32x4 facc = __builtin_amdgcn_mfma_f32_16x16x32_bf16(af, wb, cvec, 0, 0, 0);
        if (c < 18) af = ap[(c + 1)*64 + l];

        // all-gather F'[0..15] across the 4 g-groups (channel-preserving)
        float F[16];
        #pragma unroll
        for (int q = 0; q < 4; ++q) {
            float a = facc[q], b = facc[q];
            asm volatile("v_permlane16_swap_b32 %0, %1" : "+v"(a), "+v"(b));
            float a2 = a, b2 = b;
            asm volatile("v_permlane32_swap_b32 %0, %1" : "+v"(a), "+v"(a2));
            asm volatile("v_permlane32_swap_b32 %0, %1" : "+v"(b), "+v"(b2));
            F[0*4+q] = a; F[1*4+q] = b; F[2*4+q] = a2; F[3*4+q] = b2;
        }

        float avq[4];
        #pragma unroll
        for (int i = 0; i < 16; ++i) {
            const float t2 = fmaf(-Ac, y, F[i]);       // F already = c0 + Kc*F
            if (g == (i >> 2)) avq[i & 3] = z;         // raw z; DTF at store
            y = fmaf(DTF, z, y);
            z = fmaf(OmB, z, t2);
        }

        if ((c < 18) | (g < 3)) {
            *(float4*)aptr = make_float4(avq[0]*DTF, avq[1]*DTF, avq[2]*DTF, avq[3]*DTF);
        }
        aptr += 16;
    }
}

extern "C" void kernel_launch(void* const* d_in, const int* in_sizes, int n_in,
                              void* d_out, int out_size, void* d_ws, size_t ws_size,
                              hipStream_t stream) {
    (void)in_sizes; (void)n_in; (void)out_size; (void)ws_size;
    const float* state  = (const float*)d_in[0];
    const float* fc1_w  = (const float*)d_in[1];
    const float* fc1_b  = (const float*)d_in[2];
    const float* fc2m_w = (const float*)d_in[3];
    const float* fc2m_b = (const float*)d_in[4];
    const float* sig_w  = (const float*)d_in[5];
    const float* sig_b  = (const float*)d_in[6];
    const float* val_w  = (const float*)d_in[7];
    const float* val_b  = (const float*)d_in[8];
    const float* dmp_c  = (const float*)d_in[9];
    const float* dmp_s2 = (const float*)d_in[10];

    float* out     = (float*)d_out;
    float* a_out   = out;
    float* sig_out = out + A_ELEMS;
    float* v_out   = out + A_ELEMS + NBATCH*2;

    char* ws = (char*)d_ws;
    uint4*  wsPhi  = (uint4*)ws;
    float*  pbuf   = (float*)(ws + 32768);
    ushort* wbuf16 = (ushort*)(ws + 557056);

    k_head<<<dim3(257), dim3(256), 0, stream>>>(state, fc1_w, fc1_b, fc2m_w, fc2m_b,
                                                sig_w, sig_b, val_w, val_b,
                                                dmp_c, dmp_s2,
                                                sig_out, pbuf, wbuf16, wsPhi);
    k_roll<<<dim3(512), dim3(384), 0, stream>>>(wsPhi, pbuf, wbuf16, a_out, v_out);
}

// Round 17
// 27.470 us; speedup vs baseline: 2.8633x; 1.0179x over previous
//
#include <hip/hip_runtime.h>
#include <hip/hip_bf16.h>

#define NB 32
#define TS 300
#define NBATCH 16384
#define DTF (1.0f/300.0f)
#define A_ELEMS (NBATCH*2*TS)   /* 9,830,400 */

typedef __attribute__((ext_vector_type(8))) short bf16x8;
typedef __attribute__((ext_vector_type(4))) float f32x4;

static __device__ __forceinline__ ushort f2bf(float f) {
    union { __hip_bfloat16 h; ushort u; } cv;
    cv.h = __float2bfloat16(f);
    return cv.u;
}

// Single kernel, 256 blocks x 768 threads (12 waves).
// Block owns 64 batches = 128 channels.
// Phase A: waves 0-3 = R12 k_head body VERBATIM (batches blk*64 + wv*16 + b16);
//          waves 4-5 = phi table -> dedicated LDS (no aliasing anywhere);
//          waves 6-11 idle to barrier.
// Phase B: waves 0-7 = R16 rollout body (m = blk*128 + wv*16 + ch);
//          waves 8-11 = v-streamers (32 channels each; same 1:2 ratio as R16).
// Handoff via global pbuf/wbuf16 exactly as the proven 2-kernel version
// (same-block L2 round-trip); __syncthreads drains vmcnt -> visible.
__global__ __launch_bounds__(768) void k_all(
    const float* __restrict__ state,
    const float* __restrict__ fc1_w, const float* __restrict__ fc1_b,
    const float* __restrict__ fc2m_w, const float* __restrict__ fc2m_b,
    const float* __restrict__ sig_w, const float* __restrict__ sig_b,
    const float* __restrict__ val_w, const float* __restrict__ val_b,
    const float* __restrict__ dmp_c, const float* __restrict__ dmp_s2,
    float* __restrict__ sig_out, float* __restrict__ pbuf,
    ushort* __restrict__ wbuf16,
    float* __restrict__ a_out, float* __restrict__ v_out)
{
    __shared__ uint4 phiL[19*64];       // 19,456 B (dedicated)
    __shared__ uint4 bfr[640];          // 10,240 B
    __shared__ float f1s[64*4];         //  1,024 B
    __shared__ float biasl[80];         //    320 B
    __shared__ float hlds[4*16*68];     // 17,408 B
    __shared__ float ct[4*16*84];       // 21,504 B
    __shared__ float scl[4][16][2];     //    512 B   (total 70,464 B)

    const int tid = threadIdx.x;
    const int wv  = tid >> 6;
    const int l   = tid & 63;

    // ---- phase A0: staging (waves 0-3) || phi (waves 4-5) ----
    if (wv < 4) {
        for (int e = tid; e < 640; e += 256) {
            const int T = e >> 7, kk = (e >> 6) & 1, lane = e & 63;
            const int r = T*16 + (lane & 15);
            const int k0 = kk*32 + (lane >> 4)*8;
            union { ushort us[8]; uint4 v; } pk;
            if (r < 70) {
                const float* src = (r < 66) ? (fc2m_w + r*64 + k0)
                                 : (r < 68) ? (sig_w + (r-66)*64 + k0)
                                 : (val_w + (r-68)*64 + k0);
                #pragma unroll
                for (int i = 0; i < 8; ++i) pk.us[i] = f2bf(src[i]);
            } else {
                #pragma unroll
                for (int i = 0; i < 8; ++i) pk.us[i] = 0;
            }
            bfr[e] = pk.v;
        }
        if (tid < 64) {
            f1s[tid*4+0] = fc1_w[tid*3+0];
            f1s[tid*4+1] = fc1_w[tid*3+1];
            f1s[tid*4+2] = fc1_w[tid*3+2];
            f1s[tid*4+3] = fc1_b[tid];
        }
        if (tid < 80) biasl[tid] = (tid < 66) ? fc2m_b[tid] : (tid < 68) ? sig_b[tid-66]
                                 : (tid < 70) ? val_b[tid-68] : 0.0f;
    } else if (wv < 6) {
        const float l2 = log2f(1.0f - DTF);
        for (int t = tid - 256; t < 304; t += 128) {
            ushort row[NB];
            if (t < TS) {
                const float x = exp2f((float)(t + 1) * l2);
                float ps[NB]; float s = 0.0f;
                #pragma unroll
                for (int n = 0; n < NB; ++n) {
                    float d = x - dmp_c[n];
                    float p = __expf(-0.5f * d * d / dmp_s2[n]);
                    ps[n] = p; s += p;
                }
                const float inv = x / s;
                #pragma unroll
                for (int n = 0; n < NB; ++n) row[n] = f2bf(ps[n] * inv);
            } else {
                #pragma unroll
                for (int n = 0; n < NB; ++n) row[n] = 0;
            }
            #pragma unroll
            for (int g0 = 0; g0 < 4; ++g0) {
                union { ushort us[8]; uint4 v; } pk;
                #pragma unroll
                for (int e = 0; e < 8; ++e) pk.us[e] = row[g0*8 + e];
                phiL[(t >> 4)*64 + g0*16 + (t & 15)] = pk.v;
            }
        }
    }
    __syncthreads();

    // ---- phase A1: MFMA heads (waves 0-3; R12 body verbatim) ----
    if (wv < 4) {
        const int b16 = l & 15;
        const int g   = l >> 4;
        const int bbase = blockIdx.x*64 + wv*16;
        const int bglob = bbase + b16;
        const float s0 = state[bglob*3+0], s1 = state[bglob*3+1], s2 = state[bglob*3+2];

        float* hrow = hlds + wv*1088 + b16*68;
        #pragma unroll
        for (int i = 0; i < 16; ++i) {
            const int hid = g + 4*i;
            const float4 fw = *(const float4*)(f1s + hid*4);
            const float pre = fmaf(fw.x, s0, fmaf(fw.y, s1, fmaf(fw.z, s2, fw.w)));
            const float e = __expf(2.0f * pre);
            hrow[hid] = (1.0f - 2.0f/(e + 1.0f)) * 0.1f;   // tanh, overflow-safe
        }

        bf16x8 A0, A1;
        {
            const float* hr = hlds + wv*1088 + b16*68 + g*8;
            const float4 h0 = *(const float4*)(hr),      h1 = *(const float4*)(hr + 4);
            const float4 h2 = *(const float4*)(hr + 32), h3 = *(const float4*)(hr + 36);
            union { bf16x8 v; ushort u[8]; } p0, p1;
            p0.u[0]=f2bf(h0.x); p0.u[1]=f2bf(h0.y); p0.u[2]=f2bf(h0.z); p0.u[3]=f2bf(h0.w);
            p0.u[4]=f2bf(h1.x); p0.u[5]=f2bf(h1.y); p0.u[6]=f2bf(h1.z); p0.u[7]=f2bf(h1.w);
            p1.u[0]=f2bf(h2.x); p1.u[1]=f2bf(h2.y); p1.u[2]=f2bf(h2.z); p1.u[3]=f2bf(h2.w);
            p1.u[4]=f2bf(h3.x); p1.u[5]=f2bf(h3.y); p1.u[6]=f2bf(h3.z); p1.u[7]=f2bf(h3.w);
            A0 = p0.v; A1 = p1.v;
        }

        float* ctw = ct + wv*1344;
        const f32x4 zacc = {0.0f, 0.0f, 0.0f, 0.0f};
        #pragma unroll
        for (int T = 0; T < 5; ++T) {
            union { uint4 q; bf16x8 v; } B0, B1;
            B0.q = bfr[(T*2+0)*64 + l];
            B1.q = bfr[(T*2+1)*64 + l];
            f32x4 acc = __builtin_amdgcn_mfma_f32_16x16x32_bf16(A0, B0.v, zacc, 0, 0, 0);
            acc = __builtin_amdgcn_mfma_f32_16x16x32_bf16(A1, B1.v, acc, 0, 0, 0);
            const int r = T*16 + b16;
            const float bs = biasl[r];
            #pragma unroll
            for (int reg = 0; reg < 4; ++reg)
                ctw[(g*4 + reg)*84 + r] = acc[reg] + bs;
        }

        if (l < 32) {
            const int b = l & 15, d = l >> 4;
            const float goal = ctw[b*84 + d];
            const float y0 = state[(bbase + b)*3 + d];
            scl[wv][b][d] = DTF * (goal - y0);
        }

        uint* wout = (uint*)wbuf16;
        #pragma unroll 1
        for (int b = 0; b < 16; ++b) {
            if (l < 32) {
                const float2 wp = *(const float2*)(ctw + b*84 + 2 + 2*l);
                const float sc = scl[wv][b][l >> 4];
                wout[(bbase + b)*32 + l] =
                    (uint)f2bf(wp.x * sc) | ((uint)f2bf(wp.y * sc) << 16);
            }
        }
        if (l < 16) {
            const float* cb = ctw + l*84;
            const float az = fminf(fmaxf(cb[65], 0.5f), 30.0f);
            const float y0 = state[(bbase + l)*3 + 0];
            *(float4*)(pbuf + ((bbase + l)*2 + 0)*4) = make_float4(cb[0], az, y0, cb[68]);
        } else if (l < 32) {
            const int b = l - 16;
            const float* cb = ctw + b*84;
            const float az = fminf(fmaxf(cb[65], 0.5f), 30.0f);
            const float y0 = state[(bbase + b)*3 + 1];
            *(float4*)(pbuf + ((bbase + b)*2 + 1)*4) = make_float4(cb[1], az, y0, cb[69]);
        } else if (l < 48) {
            const int b = l - 32;
            const float* cb = ctw + b*84;
            const float sg0 = 1.0f / (1.0f + __expf(-cb[66])) + 0.001f;
            const float sg1 = 1.0f / (1.0f + __expf(-cb[67])) + 0.001f;
            *(float2*)(sig_out + (bbase + b)*2) = make_float2(sg0, sg1);
        }
    }
    __syncthreads();   // heads + phi done; pbuf/wbuf16 drained (vmcnt) & L2-visible

    // ---- phase B: rollout (waves 0-7) || v-streamers (waves 8-11) ----
    if (wv < 8) {
        const int ch = l & 15;
        const int g  = l >> 4;
        const int m  = (blockIdx.x << 7) + (wv << 4) + ch;

        const float4 pp = *(const float4*)(pbuf + m*4);   // {goal, az, y0, v}
        const float az = pp.y;
        const float Ac = (DTF * 0.25f) * az * az;
        const float OmB = fmaf(-DTF, az, 1.0f);
        const float c0 = Ac * pp.x;
        float y = pp.z;                                   // y0
        float z = 0.01f;
        const f32x4 cvec = {c0, c0, c0, c0};

        const bf16x8 wb = *(const bf16x8*)(wbuf16 + m*NB + g*8);   // prescaled
        const bf16x8* ap = (const bf16x8*)phiL;
        bf16x8 af = ap[l];

        float* aptr = a_out + m*TS + (g << 2);

        for (int c = 0; c < 19; ++c) {
            f32x4 facc = __builtin_amdgcn_mfma_f32_16x16x32_bf16(af, wb, cvec, 0, 0, 0);
            if (c < 18) af = ap[(c + 1)*64 + l];

            // all-gather F'[0..15] across the 4 g-groups (channel-preserving)
            float F[16];
            #pragma unroll
            for (int q = 0; q < 4; ++q) {
                float a = facc[q], b = facc[q];
                asm volatile("v_permlane16_swap_b32 %0, %1" : "+v"(a), "+v"(b));
                float a2 = a, b2 = b;
                asm volatile("v_permlane32_swap_b32 %0, %1" : "+v"(a), "+v"(a2));
                asm volatile("v_permlane32_swap_b32 %0, %1" : "+v"(b), "+v"(b2));
                F[0*4+q] = a; F[1*4+q] = b; F[2*4+q] = a2; F[3*4+q] = b2;
            }

            float avq[4];
            #pragma unroll
            for (int i = 0; i < 16; ++i) {
                const float t2 = fmaf(-Ac, y, F[i]);       // F already = c0 + Kc*F
                if (g == (i >> 2)) avq[i & 3] = z;         // raw z; DTF at store
                y = fmaf(DTF, z, y);
                z = fmaf(OmB, z, t2);
            }

            if ((c < 18) | (g < 3)) {
                *(float4*)aptr = make_float4(avq[0]*DTF, avq[1]*DTF, avq[2]*DTF, avq[3]*DTF);
            }
            aptr += 16;
        }
    } else {
        // v-streamers: 4 waves x 32 channels
        const int vw = wv - 8;
        const int mbase = (blockIdx.x << 7) + (vw << 5);
        #pragma unroll 1
        for (int r = 0; r < 32; ++r) {
            const int mch = mbase + r;
            const float fv = pbuf[mch*4 + 3];
            float4* vrow = (float4*)(v_out + mch*TS);
            const float4 vq = make_float4(fv, fv, fv, fv);
            vrow[l] = vq;
            if (l < 11) vrow[64 + l] = vq;
        }
    }
}

extern "C" void kernel_launch(void* const* d_in, const int* in_sizes, int n_in,
                              void* d_out, int out_size, void* d_ws, size_t ws_size,
                              hipStream_t stream) {
    (void)in_sizes; (void)n_in; (void)out_size; (void)ws_size;
    const float* state  = (const float*)d_in[0];
    const float* fc1_w  = (const float*)d_in[1];
    const float* fc1_b  = (const float*)d_in[2];
    const float* fc2m_w = (const float*)d_in[3];
    const float* fc2m_b = (const float*)d_in[4];
    const float* sig_w  = (const float*)d_in[5];
    const float* sig_b  = (const float*)d_in[6];
    const float* val_w  = (const float*)d_in[7];
    const float* val_b  = (const float*)d_in[8];
    const float* dmp_c  = (const float*)d_in[9];
    const float* dmp_s2 = (const float*)d_in[10];

    float* out     = (float*)d_out;
    float* a_out   = out;
    float* sig_out = out + A_ELEMS;
    float* v_out   = out + A_ELEMS + NBATCH*2;

    char* ws = (char*)d_ws;
    float*  pbuf   = (float*)(ws + 32768);
    ushort* wbuf16 = (ushort*)(ws + 557056);

    k_all<<<dim3(256), dim3(768), 0, stream>>>(state, fc1_w, fc1_b, fc2m_w, fc2m_b,
                                               sig_w, sig_b, val_w, val_b,
                                               dmp_c, dmp_s2,
                                               sig_out, pbuf, wbuf16, a_out, v_out);
}